// Round 12
// baseline (116.311 us; speedup 1.0000x reference)
//
#include <hip/hip_runtime.h>
#include <cstdint>

#define B_ 2
#define C_ 128
#define N_ 4096
#define H_ 4
#define D_ 32

typedef unsigned short ushort_t;
typedef __attribute__((ext_vector_type(8))) short bf16x8;
typedef __attribute__((ext_vector_type(4))) float f32x4;
typedef __attribute__((ext_vector_type(4))) unsigned int u32x4;

__device__ __forceinline__ ushort_t f2bf(float f) {
  unsigned int u = __builtin_bit_cast(unsigned int, f);
  u += 0x7fffu + ((u >> 16) & 1u);
  return (ushort_t)(u >> 16);
}

// async global->LDS, 16 B per lane; LDS dest = l + lane*16 (HW-linear)
__device__ __forceinline__ void stage16(const ushort_t* g, ushort_t* l) {
  __builtin_amdgcn_global_load_lds(
      (const __attribute__((address_space(1))) unsigned int*)g,
      (__attribute__((address_space(3))) unsigned int*)l, 16, 0, 0);
}

// z in {0,1}: scatter psel/pdrop; every block also converts 256 weight elems (fp32->bf16,
// Wq pre-scaled by log2(e)/sqrt(32)) so the old z=2 slice is gone.
__global__ __launch_bounds__(256) void k_prep(const float* __restrict__ psel,
                                              const float* __restrict__ pdrop,
                                              const int* __restrict__ isel,
                                              const int* __restrict__ idrop,
                                              const float* __restrict__ Wq,
                                              const float* __restrict__ Wk,
                                              const float* __restrict__ Wv,
                                              const float* __restrict__ Wsk,
                                              ushort_t* __restrict__ xT,
                                              ushort_t* __restrict__ Wb) {
  int z = blockIdx.z;
  int b = blockIdx.y;
  int t = threadIdx.x;
  {
    int gid = (((z * 2 + b) * 64 + blockIdx.x) << 8) + t;  // 0..65535
    int m = gid >> 14, e = gid & 16383;
    const float* src = (m == 0) ? Wq : (m == 1) ? Wk : (m == 2) ? Wv : Wsk;
    float sc = (m == 0) ? 0.25506552f : 1.0f;
    Wb[m * 16384 + e] = f2bf(src[e] * sc);
  }
  const float* src = z ? pdrop : psel;
  const int* idx = z ? idrop : isel;
  __shared__ ushort_t tile[128][34];
  int i0 = blockIdx.x * 32;
  {
    int c = t >> 1, ih = (t & 1) * 16;
    const float4* p = (const float4*)(src + ((size_t)(b * 128 + c) * 2048 + i0 + ih));
#pragma unroll
    for (int g = 0; g < 4; ++g) {
      float4 v = p[g];
      tile[c][ih + g * 4 + 0] = f2bf(v.x);
      tile[c][ih + g * 4 + 1] = f2bf(v.y);
      tile[c][ih + g * 4 + 2] = f2bf(v.z);
      tile[c][ih + g * 4 + 3] = f2bf(v.w);
    }
  }
  __syncthreads();
  {
    int i = t >> 3, c0 = (t & 7) * 16;
    int n = idx[b * 2048 + i0 + i];
    alignas(16) ushort_t outv[16];
#pragma unroll
    for (int j = 0; j < 16; ++j) outv[j] = tile[c0 + j][i];
    uint4* q = (uint4*)(xT + ((size_t)(b * 4096 + n) * 128 + c0));
    q[0] = *(uint4*)outv; q[1] = *(uint4*)(outv + 8);
  }
}

// y[o][n-tile 64] = W . x  for wt: 0=K (write Kb [B,H,N,32]), 1=V (write Vt [B,H,32,N],
// key-permuted pi(p)=(p>>3)*4+(p&3)+((p&4)<<2) within 32-chunks), 2=skip (fp32 out).
__global__ __launch_bounds__(256) void k_proj(const ushort_t* __restrict__ xT,
                                              const float* __restrict__ pcd,
                                              const ushort_t* __restrict__ Wb,
                                              ushort_t* __restrict__ Kb,
                                              ushort_t* __restrict__ Vt,
                                              float* __restrict__ outp) {
  __shared__ ushort_t ldsT[64][136];
  __shared__ float y[128][66];
  int n0 = blockIdx.x * 64, wt = blockIdx.y, b = blockIdx.z, t = threadIdx.x;
  int wave = t >> 6, lane = t & 63, lr = lane & 15, quad = lane >> 4;
  const ushort_t* W = Wb + (size_t)(wt + 1) * 16384;  // Wk, Wv, Wsk

  if (wt == 2) {
#pragma unroll
    for (int rep = 0; rep < 4; ++rep) {
      int idx = rep * 256 + t;
      int c = idx >> 3, ng = (idx & 7) * 8;
      const float4* p = (const float4*)(pcd + ((size_t)(b * 128 + c) * 4096 + n0 + ng));
      float4 v0 = p[0], v1 = p[1];
      ldsT[ng + 0][c] = f2bf(v0.x); ldsT[ng + 1][c] = f2bf(v0.y);
      ldsT[ng + 2][c] = f2bf(v0.z); ldsT[ng + 3][c] = f2bf(v0.w);
      ldsT[ng + 4][c] = f2bf(v1.x); ldsT[ng + 5][c] = f2bf(v1.y);
      ldsT[ng + 6][c] = f2bf(v1.z); ldsT[ng + 7][c] = f2bf(v1.w);
    }
    __syncthreads();
  }

  f32x4 acc[2][4];
#pragma unroll
  for (int mt = 0; mt < 2; ++mt)
#pragma unroll
    for (int nt = 0; nt < 4; ++nt) acc[mt][nt] = (f32x4){0.f, 0.f, 0.f, 0.f};
#pragma unroll
  for (int kc = 0; kc < 128; kc += 32) {
    bf16x8 a[2], bb[4];
#pragma unroll
    for (int mt = 0; mt < 2; ++mt)
      a[mt] = *(const bf16x8*)(W + (size_t)(wave * 32 + mt * 16 + lr) * 128 + kc + quad * 8);
    if (wt == 2) {
#pragma unroll
      for (int nt = 0; nt < 4; ++nt)
        bb[nt] = *(const bf16x8*)(&ldsT[nt * 16 + lr][kc + quad * 8]);
    } else {
#pragma unroll
      for (int nt = 0; nt < 4; ++nt)
        bb[nt] = *(const bf16x8*)(xT + ((size_t)(b * 4096 + n0 + nt * 16 + lr)) * 128 + kc + quad * 8);
    }
#pragma unroll
    for (int mt = 0; mt < 2; ++mt)
#pragma unroll
      for (int nt = 0; nt < 4; ++nt)
        acc[mt][nt] = __builtin_amdgcn_mfma_f32_16x16x32_bf16(a[mt], bb[nt], acc[mt][nt], 0, 0, 0);
  }

  if (wt == 2) {
#pragma unroll
    for (int mt = 0; mt < 2; ++mt)
#pragma unroll
      for (int nt = 0; nt < 4; ++nt)
#pragma unroll
        for (int r = 0; r < 4; ++r) {
          int o = wave * 32 + mt * 16 + quad * 4 + r;
          outp[(size_t)(b * 128 + o) * 4096 + n0 + nt * 16 + lr] = acc[mt][nt][r];
        }
    return;
  }

#pragma unroll
  for (int mt = 0; mt < 2; ++mt)
#pragma unroll
    for (int nt = 0; nt < 4; ++nt)
#pragma unroll
      for (int r = 0; r < 4; ++r)
        y[wave * 32 + mt * 16 + quad * 4 + r][nt * 16 + lr] = acc[mt][nt][r];
  __syncthreads();

  if (wt == 0) {
    // K: [B,H,N,32], d-contiguous
    int n = t >> 2, dq = (t & 3) * 8;
#pragma unroll
    for (int h = 0; h < 4; ++h) {
      alignas(16) ushort_t vals[8];
#pragma unroll
      for (int j = 0; j < 8; ++j) vals[j] = f2bf(y[h * 32 + dq + j][n]);
      *(uint4*)(Kb + (((size_t)(b * 4 + h) * 4096 + n0 + n) * 32 + dq)) = *(uint4*)vals;
    }
  } else {
    // V: [B,H,32,N]; position p within a 32-chunk holds key pi(p)=(p>>3)*4+(p&3)+((p&4)<<2)
    int o = t >> 1, half = t & 1;
    int h = o >> 5, d = o & 31;
    alignas(16) ushort_t vals[32];
#pragma unroll
    for (int j = 0; j < 32; ++j) {
      int c = half * 32 + ((j >> 3) * 4 + (j & 3) + ((j & 4) << 2));
      vals[j] = f2bf(y[o][c]);
    }
    uint4* dst = (uint4*)(Vt + ((size_t)(b * 4 + h) * 32 + d) * 4096 + n0 + half * 32);
#pragma unroll
    for (int g = 0; g < 4; ++g) dst[g] = *(uint4*)(vals + g * 8);
  }
}

// Flash attention: 512 blocks x 512 thr (2 blocks/CU -> two independent barrier domains
// per CU). Block = 64 q (2 q-waves) x split-K x4 (kq = wave>>1, keys [kq*1024,+1024)),
// 64-key double-buffered LDS chunks via global_load_lds. Rowsum via ones-MFMA.
__global__ __launch_bounds__(512, 4) void k_attn(const ushort_t* __restrict__ xT,
                                                 const ushort_t* __restrict__ Wb,
                                                 const ushort_t* __restrict__ Kb,
                                                 const ushort_t* __restrict__ Vt,
                                                 float* __restrict__ outp) {
  __shared__ ushort_t qT[2][32 * 40];
  __shared__ ushort_t stg[4][2][4096];  // [kq][db][ K elems 0..2047 | V elems 2048..4095 ]

  int bh = blockIdx.x & 7;  // XCD pin
  int q0 = (blockIdx.x >> 3) * 64;
  int b = bh >> 2, h = bh & 3;
  int t = threadIdx.x, wave = t >> 6, lane = t & 63, lr = lane & 15, quad = lane >> 4;
  int qh = wave & 1, kq = wave >> 1;
  int qbase = q0 + qh * 32;
  const ushort_t* xb = xT + (size_t)b * N_ * 128;
  const ushort_t* wqp = Wb + (size_t)h * 32 * 128;  // Wq (pre-scaled) at offset 0
  const ushort_t* Kp = Kb + (size_t)bh * N_ * 32;
  const ushort_t* Vp = Vt + (size_t)bh * 32 * N_;
  const int ks = kq * 1024;

  // chunk = 64 keys: K 4 KB as [d-oct s][key 64][8d]; V 4 KB as [pos-oct][d 32][8pos]
#define STAGE_CHUNK(kcn, buf)                                                      \
  {                                                                                \
    ushort_t* kb_ = stg[kq][buf];                                                  \
    ushort_t* vb_ = kb_ + 2048;                                                    \
    _Pragma("unroll") for (int j = 0; j < 2; ++j) {                                \
      int s = qh * 2 + j;                                                          \
      stage16(Kp + (size_t)((kcn) + lane) * 32 + s * 8, kb_ + s * 512);            \
      int I = s * 64 + lane;                                                       \
      stage16(Vp + (size_t)(I & 31) * N_ + (kcn) + ((I >> 5) * 8), vb_ + s * 512); \
    }                                                                              \
  }

  // ---- Q projection (kq==0 waves; wave qh projects queries qbase..qbase+31) ----
  if (kq == 0) {
    f32x4 accq[2][2];
#pragma unroll
    for (int mt = 0; mt < 2; ++mt)
#pragma unroll
      for (int nt = 0; nt < 2; ++nt) accq[mt][nt] = (f32x4){0.f, 0.f, 0.f, 0.f};
#pragma unroll
    for (int kc = 0; kc < 128; kc += 32) {
      bf16x8 ax[2], bw[2];
#pragma unroll
      for (int mt = 0; mt < 2; ++mt)
        ax[mt] = *(const bf16x8*)(xb + (size_t)(qbase + mt * 16 + lr) * 128 + kc + quad * 8);
#pragma unroll
      for (int nt = 0; nt < 2; ++nt)
        bw[nt] = *(const bf16x8*)(wqp + (size_t)(nt * 16 + lr) * 128 + kc + quad * 8);
#pragma unroll
      for (int mt = 0; mt < 2; ++mt)
#pragma unroll
        for (int nt = 0; nt < 2; ++nt)
          accq[mt][nt] = __builtin_amdgcn_mfma_f32_16x16x32_bf16(ax[mt], bw[nt], accq[mt][nt], 0, 0, 0);
    }
#pragma unroll
    for (int mt = 0; mt < 2; ++mt)
#pragma unroll
      for (int nt = 0; nt < 2; ++nt)
#pragma unroll
        for (int r = 0; r < 4; ++r)
          qT[qh][(mt * 16 + quad * 4 + r) * 40 + nt * 16 + lr] = f2bf(accq[mt][nt][r]);
  }

  STAGE_CHUNK(ks, 0);
  __syncthreads();

  bf16x8 aq0 = *(const bf16x8*)(&qT[qh][lr * 40 + quad * 8]);
  bf16x8 aq1 = *(const bf16x8*)(&qT[qh][(16 + lr) * 40 + quad * 8]);

  bf16x8 vones;
#pragma unroll
  for (int j = 0; j < 8; ++j) vones[j] = (short)0x3F80;

  f32x4 accO[2][2];  // [qfrag][dtile]
  f32x4 accR[2];     // [qfrag] rowsum via ones-MFMA
#pragma unroll
  for (int qf = 0; qf < 2; ++qf) {
#pragma unroll
    for (int dt = 0; dt < 2; ++dt) accO[qf][dt] = (f32x4){0.f, 0.f, 0.f, 0.f};
    accR[qf] = (f32x4){0.f, 0.f, 0.f, 0.f};
  }

  for (int it = 0; it < 16; ++it) {
    int cur = it & 1;
    if (it + 1 < 16) STAGE_CHUNK(ks + (it + 1) * 64, cur ^ 1);
    const ushort_t* kb = stg[kq][cur];
    const ushort_t* vb = kb + 2048;
#pragma unroll
    for (int g = 0; g < 2; ++g) {
      bf16x8 bk0 = *(const bf16x8*)(kb + (quad * 64 + g * 32 + lr) * 8);
      bf16x8 bk1 = *(const bf16x8*)(kb + (quad * 64 + g * 32 + 16 + lr) * 8);
      bf16x8 bv0 = *(const bf16x8*)(vb + ((g * 4 + quad) * 32 + lr) * 8);
      bf16x8 bv1 = *(const bf16x8*)(vb + ((g * 4 + quad) * 32 + 16 + lr) * 8);

      f32x4 z = {0.f, 0.f, 0.f, 0.f};
      f32x4 s0 = __builtin_amdgcn_mfma_f32_16x16x32_bf16(bk0, aq0, z, 0, 0, 0);
      f32x4 s1 = __builtin_amdgcn_mfma_f32_16x16x32_bf16(bk1, aq0, z, 0, 0, 0);
      f32x4 s2 = __builtin_amdgcn_mfma_f32_16x16x32_bf16(bk0, aq1, z, 0, 0, 0);
      f32x4 s3 = __builtin_amdgcn_mfma_f32_16x16x32_bf16(bk1, aq1, z, 0, 0, 0);
      float p0[4], p1[4], p2[4], p3[4];
#pragma unroll
      for (int r = 0; r < 4; ++r) {
        p0[r] = __builtin_amdgcn_exp2f(s0[r]);
        p1[r] = __builtin_amdgcn_exp2f(s1[r]);
        p2[r] = __builtin_amdgcn_exp2f(s2[r]);
        p3[r] = __builtin_amdgcn_exp2f(s3[r]);
      }
      u32x4 pk0, pk1;
      pk0.x = __builtin_amdgcn_perm(__builtin_bit_cast(unsigned int, p0[1]),
                                    __builtin_bit_cast(unsigned int, p0[0]), 0x07060302u);
      pk0.y = __builtin_amdgcn_perm(__builtin_bit_cast(unsigned int, p0[3]),
                                    __builtin_bit_cast(unsigned int, p0[2]), 0x07060302u);
      pk0.z = __builtin_amdgcn_perm(__builtin_bit_cast(unsigned int, p1[1]),
                                    __builtin_bit_cast(unsigned int, p1[0]), 0x07060302u);
      pk0.w = __builtin_amdgcn_perm(__builtin_bit_cast(unsigned int, p1[3]),
                                    __builtin_bit_cast(unsigned int, p1[2]), 0x07060302u);
      pk1.x = __builtin_amdgcn_perm(__builtin_bit_cast(unsigned int, p2[1]),
                                    __builtin_bit_cast(unsigned int, p2[0]), 0x07060302u);
      pk1.y = __builtin_amdgcn_perm(__builtin_bit_cast(unsigned int, p2[3]),
                                    __builtin_bit_cast(unsigned int, p2[2]), 0x07060302u);
      pk1.z = __builtin_amdgcn_perm(__builtin_bit_cast(unsigned int, p3[1]),
                                    __builtin_bit_cast(unsigned int, p3[0]), 0x07060302u);
      pk1.w = __builtin_amdgcn_perm(__builtin_bit_cast(unsigned int, p3[3]),
                                    __builtin_bit_cast(unsigned int, p3[2]), 0x07060302u);
      bf16x8 ap0 = __builtin_bit_cast(bf16x8, pk0);
      bf16x8 ap1 = __builtin_bit_cast(bf16x8, pk1);
      accO[0][0] = __builtin_amdgcn_mfma_f32_16x16x32_bf16(ap0, bv0, accO[0][0], 0, 0, 0);
      accO[0][1] = __builtin_amdgcn_mfma_f32_16x16x32_bf16(ap0, bv1, accO[0][1], 0, 0, 0);
      accO[1][0] = __builtin_amdgcn_mfma_f32_16x16x32_bf16(ap1, bv0, accO[1][0], 0, 0, 0);
      accO[1][1] = __builtin_amdgcn_mfma_f32_16x16x32_bf16(ap1, bv1, accO[1][1], 0, 0, 0);
      accR[0] = __builtin_amdgcn_mfma_f32_16x16x32_bf16(ap0, vones, accR[0], 0, 0, 0);
      accR[1] = __builtin_amdgcn_mfma_f32_16x16x32_bf16(ap1, vones, accR[1], 0, 0, 0);
    }
    __syncthreads();
  }

  // ---- combine 4 key-quarters (stg no longer needed: alias pbuf/obuf) ----
  float* pbuf = (float*)&stg[0][0][0];   // 3 x 2 x 64 x 24 floats = 36,864 B
  float* obuf = pbuf + 9216;             // 2 x 32 x 33 floats

  if (kq != 0) {
    float* pb = pbuf + (((kq - 1) * 2 + qh) * 64 + lane) * 24;
#pragma unroll
    for (int qf = 0; qf < 2; ++qf) {
#pragma unroll
      for (int dt = 0; dt < 2; ++dt)
#pragma unroll
        for (int r = 0; r < 4; ++r) pb[qf * 8 + dt * 4 + r] = accO[qf][dt][r];
#pragma unroll
      for (int r = 0; r < 4; ++r) pb[16 + qf * 4 + r] = accR[qf][r];
    }
  }
  __syncthreads();
  if (kq != 0) return;

#pragma unroll
  for (int j = 0; j < 3; ++j) {
    const float* pb = pbuf + ((j * 2 + qh) * 64 + lane) * 24;
#pragma unroll
    for (int qf = 0; qf < 2; ++qf) {
#pragma unroll
      for (int dt = 0; dt < 2; ++dt)
#pragma unroll
        for (int r = 0; r < 4; ++r) accO[qf][dt][r] += pb[qf * 8 + dt * 4 + r];
#pragma unroll
      for (int r = 0; r < 4; ++r) accR[qf][r] += pb[16 + qf * 4 + r];
    }
  }

  // rinv directly from accR (C-layout row = q = quad*4+r matches the write below)
  float* ob = obuf + qh * 32 * 33;
#pragma unroll
  for (int qf = 0; qf < 2; ++qf) {
    float rinv[4];
#pragma unroll
    for (int r = 0; r < 4; ++r) rinv[r] = 1.0f / accR[qf][r];
#pragma unroll
    for (int dt = 0; dt < 2; ++dt)
#pragma unroll
      for (int r = 0; r < 4; ++r)
        ob[(dt * 16 + lr) * 33 + qf * 16 + quad * 4 + r] = accO[qf][dt][r] * rinv[r];
  }

  // ---- epilogue: out[b][h*32+d][qbase + q] += ob[d][q]  (fp32 RMW, 32 q/wave) ----
  int d = lane >> 1, q16 = (lane & 1) * 16;
  float* po = outp + ((size_t)(b * 128 + h * 32 + d)) * N_ + qbase + q16;
#pragma unroll
  for (int g = 0; g < 4; ++g) {
    float4 r0 = *(float4*)(po + g * 4);
    r0.x += ob[d * 33 + q16 + g * 4 + 0];
    r0.y += ob[d * 33 + q16 + g * 4 + 1];
    r0.z += ob[d * 33 + q16 + g * 4 + 2];
    r0.w += ob[d * 33 + q16 + g * 4 + 3];
    *(float4*)(po + g * 4) = r0;
  }
}

extern "C" void kernel_launch(void* const* d_in, const int* in_sizes, int n_in,
                              void* d_out, int out_size, void* d_ws, size_t ws_size,
                              hipStream_t stream) {
  const float* pcd_up = (const float*)d_in[0];
  const float* psel   = (const float*)d_in[1];
  const float* pdrop  = (const float*)d_in[2];
  const float* Wq  = (const float*)d_in[4];
  const float* Wk  = (const float*)d_in[5];
  const float* Wv  = (const float*)d_in[6];
  const float* Wsk = (const float*)d_in[7];
  const int* isel  = (const int*)d_in[8];
  const int* idrop = (const int*)d_in[9];
  float* out = (float*)d_out;

  ushort_t* xT = (ushort_t*)d_ws;               // [B][N][C]      1,048,576
  ushort_t* Wb = xT + 1048576;                  // 4 x 128x128       65,536
  ushort_t* Kb = Wb + 65536;                    // [B][H][N][32]  1,048,576
  ushort_t* Vt = Kb + 1048576;                  // [B][H][32][N]  1,048,576
  // total 6.125 MB

  hipLaunchKernelGGL(k_prep, dim3(64, 2, 2), dim3(256), 0, stream,
                     psel, pdrop, isel, idrop, Wq, Wk, Wv, Wsk, xT, Wb);
  hipLaunchKernelGGL(k_proj, dim3(64, 3, 2), dim3(256), 0, stream,
                     xT, pcd_up, Wb, Kb, Vt, out);
  hipLaunchKernelGGL(k_attn, dim3(512), dim3(512), 0, stream, xT, Wb, Kb, Vt, out);
}

// Round 13
// 112.878 us; speedup vs baseline: 1.0304x; 1.0304x over previous
//
#include <hip/hip_runtime.h>
#include <cstdint>

#define B_ 2
#define C_ 128
#define N_ 4096
#define H_ 4
#define D_ 32

typedef unsigned short ushort_t;
typedef __attribute__((ext_vector_type(8))) short bf16x8;
typedef __attribute__((ext_vector_type(4))) float f32x4;
typedef __attribute__((ext_vector_type(4))) unsigned int u32x4;

__device__ __forceinline__ ushort_t f2bf(float f) {
  unsigned int u = __builtin_bit_cast(unsigned int, f);
  u += 0x7fffu + ((u >> 16) & 1u);
  return (ushort_t)(u >> 16);
}

// async global->LDS, 16 B per lane; LDS dest = l + lane*16 (HW-linear)
__device__ __forceinline__ void stage16(const ushort_t* g, ushort_t* l) {
  __builtin_amdgcn_global_load_lds(
      (const __attribute__((address_space(1))) unsigned int*)g,
      (__attribute__((address_space(3))) unsigned int*)l, 16, 0, 0);
}

// z in {0,1}: scatter psel/pdrop; every block also converts 256 weight elems (fp32->bf16,
// Wq pre-scaled by log2(e)/sqrt(32)).
__global__ __launch_bounds__(256) void k_prep(const float* __restrict__ psel,
                                              const float* __restrict__ pdrop,
                                              const int* __restrict__ isel,
                                              const int* __restrict__ idrop,
                                              const float* __restrict__ Wq,
                                              const float* __restrict__ Wk,
                                              const float* __restrict__ Wv,
                                              const float* __restrict__ Wsk,
                                              ushort_t* __restrict__ xT,
                                              ushort_t* __restrict__ Wb) {
  int z = blockIdx.z;
  int b = blockIdx.y;
  int t = threadIdx.x;
  {
    int gid = (((z * 2 + b) * 64 + blockIdx.x) << 8) + t;  // 0..65535
    int m = gid >> 14, e = gid & 16383;
    const float* src = (m == 0) ? Wq : (m == 1) ? Wk : (m == 2) ? Wv : Wsk;
    float sc = (m == 0) ? 0.25506552f : 1.0f;
    Wb[m * 16384 + e] = f2bf(src[e] * sc);
  }
  const float* src = z ? pdrop : psel;
  const int* idx = z ? idrop : isel;
  __shared__ ushort_t tile[128][34];
  int i0 = blockIdx.x * 32;
  {
    int c = t >> 1, ih = (t & 1) * 16;
    const float4* p = (const float4*)(src + ((size_t)(b * 128 + c) * 2048 + i0 + ih));
#pragma unroll
    for (int g = 0; g < 4; ++g) {
      float4 v = p[g];
      tile[c][ih + g * 4 + 0] = f2bf(v.x);
      tile[c][ih + g * 4 + 1] = f2bf(v.y);
      tile[c][ih + g * 4 + 2] = f2bf(v.z);
      tile[c][ih + g * 4 + 3] = f2bf(v.w);
    }
  }
  __syncthreads();
  {
    int i = t >> 3, c0 = (t & 7) * 16;
    int n = idx[b * 2048 + i0 + i];
    alignas(16) ushort_t outv[16];
#pragma unroll
    for (int j = 0; j < 16; ++j) outv[j] = tile[c0 + j][i];
    uint4* q = (uint4*)(xT + ((size_t)(b * 4096 + n) * 128 + c0));
    q[0] = *(uint4*)outv; q[1] = *(uint4*)(outv + 8);
  }
}

// K/V projection only. wt: 0=K (Kb [B,H,N,32]), 1=V (Vt [B,H,32,N], key-permuted
// pi(p)=(p>>3)*4+(p&3)+((p&4)<<2) within 32-chunks).
__global__ __launch_bounds__(256) void k_proj(const ushort_t* __restrict__ xT,
                                              const ushort_t* __restrict__ Wb,
                                              ushort_t* __restrict__ Kb,
                                              ushort_t* __restrict__ Vt) {
  __shared__ float y[128][66];
  int n0 = blockIdx.x * 64, wt = blockIdx.y, b = blockIdx.z, t = threadIdx.x;
  int wave = t >> 6, lane = t & 63, lr = lane & 15, quad = lane >> 4;
  const ushort_t* W = Wb + (size_t)(wt + 1) * 16384;  // Wk, Wv

  f32x4 acc[2][4];
#pragma unroll
  for (int mt = 0; mt < 2; ++mt)
#pragma unroll
    for (int nt = 0; nt < 4; ++nt) acc[mt][nt] = (f32x4){0.f, 0.f, 0.f, 0.f};
#pragma unroll
  for (int kc = 0; kc < 128; kc += 32) {
    bf16x8 a[2], bb[4];
#pragma unroll
    for (int mt = 0; mt < 2; ++mt)
      a[mt] = *(const bf16x8*)(W + (size_t)(wave * 32 + mt * 16 + lr) * 128 + kc + quad * 8);
#pragma unroll
    for (int nt = 0; nt < 4; ++nt)
      bb[nt] = *(const bf16x8*)(xT + ((size_t)(b * 4096 + n0 + nt * 16 + lr)) * 128 + kc + quad * 8);
#pragma unroll
    for (int mt = 0; mt < 2; ++mt)
#pragma unroll
      for (int nt = 0; nt < 4; ++nt)
        acc[mt][nt] = __builtin_amdgcn_mfma_f32_16x16x32_bf16(a[mt], bb[nt], acc[mt][nt], 0, 0, 0);
  }

#pragma unroll
  for (int mt = 0; mt < 2; ++mt)
#pragma unroll
    for (int nt = 0; nt < 4; ++nt)
#pragma unroll
      for (int r = 0; r < 4; ++r)
        y[wave * 32 + mt * 16 + quad * 4 + r][nt * 16 + lr] = acc[mt][nt][r];
  __syncthreads();

  if (wt == 0) {
    int n = t >> 2, dq = (t & 3) * 8;
#pragma unroll
    for (int h = 0; h < 4; ++h) {
      alignas(16) ushort_t vals[8];
#pragma unroll
      for (int j = 0; j < 8; ++j) vals[j] = f2bf(y[h * 32 + dq + j][n]);
      *(uint4*)(Kb + (((size_t)(b * 4 + h) * 4096 + n0 + n) * 32 + dq)) = *(uint4*)vals;
    }
  } else {
    int o = t >> 1, half = t & 1;
    int h = o >> 5, d = o & 31;
    alignas(16) ushort_t vals[32];
#pragma unroll
    for (int j = 0; j < 32; ++j) {
      int c = half * 32 + ((j >> 3) * 4 + (j & 3) + ((j & 4) << 2));
      vals[j] = f2bf(y[o][c]);
    }
    uint4* dst = (uint4*)(Vt + ((size_t)(b * 4 + h) * 32 + d) * 4096 + n0 + half * 32);
#pragma unroll
    for (int g = 0; g < 4; ++g) dst[g] = *(uint4*)(vals + g * 8);
  }
}

// Flash attention + fused skip GEMM. 256 blocks x 1024 thr: 128 q/block, split-K x4
// (kq = wave>>2, keys [kq*1024,+1024)), per-quarter double-buffered 128-key LDS staging.
// kq==0 waves project Q; kq==1 waves also compute the skip tile (Wsk . pcd) for this
// block's 32d x 128q outputs. Epilogue writes out = attn/l + skip (no RMW).
__global__ __launch_bounds__(1024) void k_attn(const ushort_t* __restrict__ xT,
                                               const float* __restrict__ pcd,
                                               const ushort_t* __restrict__ Wb,
                                               const ushort_t* __restrict__ Kb,
                                               const ushort_t* __restrict__ Vt,
                                               float* __restrict__ outp) {
  __shared__ ushort_t qT[4][32 * 40];
  __shared__ ushort_t stg[4][2][8192];  // [kq][db][ K: 0..4095 | V: 4096..8191 ]

  int bh = blockIdx.x & 7;  // XCD pin
  int q0 = (blockIdx.x >> 3) * 128;
  int b = bh >> 2, h = bh & 3;
  int t = threadIdx.x, wave = t >> 6, lane = t & 63, lr = lane & 15, quad = lane >> 4;
  int qh = wave & 3, kq = wave >> 2, lw = qh;
  int qbase = q0 + qh * 32;
  const ushort_t* xb = xT + (size_t)b * N_ * 128;
  const ushort_t* wqp = Wb + (size_t)h * 32 * 128;  // Wq (pre-scaled) at offset 0
  const ushort_t* Kp = Kb + (size_t)bh * N_ * 32;
  const ushort_t* Vp = Vt + (size_t)bh * 32 * N_;
  const int ks = kq * 1024;

#define STAGE_CHUNK(kcn, buf)                                                          \
  {                                                                                    \
    ushort_t* kb_ = stg[kq][buf];                                                      \
    ushort_t* vb_ = kb_ + 4096;                                                        \
    _Pragma("unroll") for (int j = 0; j < 2; ++j) {                                    \
      int s = lw * 2 + j;                                                              \
      stage16(Kp + (size_t)((kcn) + (s & 1) * 64 + lane) * 32 + (s >> 1) * 8,          \
              kb_ + s * 512);                                                          \
      int I = s * 64 + lane;                                                           \
      stage16(Vp + (size_t)(I & 31) * N_ + (kcn) + ((I >> 5) * 8), vb_ + s * 512);     \
    }                                                                                  \
  }

  // ---- Q projection (kq==0 waves; each projects its 32 queries) ----
  if (kq == 0) {
    f32x4 accq[2][2];
#pragma unroll
    for (int mt = 0; mt < 2; ++mt)
#pragma unroll
      for (int nt = 0; nt < 2; ++nt) accq[mt][nt] = (f32x4){0.f, 0.f, 0.f, 0.f};
#pragma unroll
    for (int kc = 0; kc < 128; kc += 32) {
      bf16x8 ax[2], bw[2];
#pragma unroll
      for (int mt = 0; mt < 2; ++mt)
        ax[mt] = *(const bf16x8*)(xb + (size_t)(qbase + mt * 16 + lr) * 128 + kc + quad * 8);
#pragma unroll
      for (int nt = 0; nt < 2; ++nt)
        bw[nt] = *(const bf16x8*)(wqp + (size_t)(nt * 16 + lr) * 128 + kc + quad * 8);
#pragma unroll
      for (int mt = 0; mt < 2; ++mt)
#pragma unroll
        for (int nt = 0; nt < 2; ++nt)
          accq[mt][nt] = __builtin_amdgcn_mfma_f32_16x16x32_bf16(ax[mt], bw[nt], accq[mt][nt], 0, 0, 0);
    }
#pragma unroll
    for (int mt = 0; mt < 2; ++mt)
#pragma unroll
      for (int nt = 0; nt < 2; ++nt)
#pragma unroll
        for (int r = 0; r < 4; ++r)
          qT[qh][(mt * 16 + quad * 4 + r) * 40 + nt * 16 + lr] = f2bf(accq[mt][nt][r]);
  }

  STAGE_CHUNK(ks, 0);

  // ---- skip GEMM (kq==1 waves): accS[q=mt*16+quad*4+r][d=nt*16+lr], K=128 ----
  f32x4 accS[2][2];
#pragma unroll
  for (int mt = 0; mt < 2; ++mt)
#pragma unroll
    for (int nt = 0; nt < 2; ++nt) accS[mt][nt] = (f32x4){0.f, 0.f, 0.f, 0.f};
  if (kq == 1) {
    const ushort_t* wsk = Wb + 3 * 16384 + (size_t)h * 32 * 128;
#pragma unroll
    for (int kc = 0; kc < 128; kc += 32) {
      bf16x8 aS[2], bW[2];
#pragma unroll
      for (int mt = 0; mt < 2; ++mt) {
        alignas(16) ushort_t tmp[8];
#pragma unroll
        for (int j = 0; j < 8; ++j)
          tmp[j] = f2bf(pcd[((size_t)(b * 128 + kc + quad * 8 + j)) * 4096 + qbase + mt * 16 + lr]);
        aS[mt] = *(bf16x8*)tmp;
      }
#pragma unroll
      for (int nt = 0; nt < 2; ++nt)
        bW[nt] = *(const bf16x8*)(wsk + (size_t)(nt * 16 + lr) * 128 + kc + quad * 8);
#pragma unroll
      for (int mt = 0; mt < 2; ++mt)
#pragma unroll
        for (int nt = 0; nt < 2; ++nt)
          accS[mt][nt] = __builtin_amdgcn_mfma_f32_16x16x32_bf16(aS[mt], bW[nt], accS[mt][nt], 0, 0, 0);
    }
  }
  __syncthreads();

  bf16x8 aq0 = *(const bf16x8*)(&qT[qh][lr * 40 + quad * 8]);
  bf16x8 aq1 = *(const bf16x8*)(&qT[qh][(16 + lr) * 40 + quad * 8]);

  bf16x8 vones;
#pragma unroll
  for (int j = 0; j < 8; ++j) vones[j] = (short)0x3F80;

  f32x4 accO[2][2];
  f32x4 accR[2];
#pragma unroll
  for (int qf = 0; qf < 2; ++qf) {
#pragma unroll
    for (int dt = 0; dt < 2; ++dt) accO[qf][dt] = (f32x4){0.f, 0.f, 0.f, 0.f};
    accR[qf] = (f32x4){0.f, 0.f, 0.f, 0.f};
  }

  for (int it = 0; it < 8; ++it) {
    int cur = it & 1;
    if (it + 1 < 8) STAGE_CHUNK(ks + (it + 1) * 128, cur ^ 1);
    const ushort_t* kb = stg[kq][cur];
    const ushort_t* vb = kb + 4096;
#pragma unroll
    for (int g = 0; g < 4; ++g) {
      bf16x8 bk0 = *(const bf16x8*)(kb + (quad * 128 + g * 32 + lr) * 8);
      bf16x8 bk1 = *(const bf16x8*)(kb + (quad * 128 + g * 32 + 16 + lr) * 8);
      bf16x8 bv0 = *(const bf16x8*)(vb + ((g * 4 + quad) * 32 + lr) * 8);
      bf16x8 bv1 = *(const bf16x8*)(vb + ((g * 4 + quad) * 32 + 16 + lr) * 8);

      f32x4 z = {0.f, 0.f, 0.f, 0.f};
      f32x4 s0 = __builtin_amdgcn_mfma_f32_16x16x32_bf16(bk0, aq0, z, 0, 0, 0);
      f32x4 s1 = __builtin_amdgcn_mfma_f32_16x16x32_bf16(bk1, aq0, z, 0, 0, 0);
      f32x4 s2 = __builtin_amdgcn_mfma_f32_16x16x32_bf16(bk0, aq1, z, 0, 0, 0);
      f32x4 s3 = __builtin_amdgcn_mfma_f32_16x16x32_bf16(bk1, aq1, z, 0, 0, 0);
      float p0[4], p1[4], p2[4], p3[4];
#pragma unroll
      for (int r = 0; r < 4; ++r) {
        p0[r] = __builtin_amdgcn_exp2f(s0[r]);
        p1[r] = __builtin_amdgcn_exp2f(s1[r]);
        p2[r] = __builtin_amdgcn_exp2f(s2[r]);
        p3[r] = __builtin_amdgcn_exp2f(s3[r]);
      }
      u32x4 pk0, pk1;
      pk0.x = __builtin_amdgcn_perm(__builtin_bit_cast(unsigned int, p0[1]),
                                    __builtin_bit_cast(unsigned int, p0[0]), 0x07060302u);
      pk0.y = __builtin_amdgcn_perm(__builtin_bit_cast(unsigned int, p0[3]),
                                    __builtin_bit_cast(unsigned int, p0[2]), 0x07060302u);
      pk0.z = __builtin_amdgcn_perm(__builtin_bit_cast(unsigned int, p1[1]),
                                    __builtin_bit_cast(unsigned int, p1[0]), 0x07060302u);
      pk0.w = __builtin_amdgcn_perm(__builtin_bit_cast(unsigned int, p1[3]),
                                    __builtin_bit_cast(unsigned int, p1[2]), 0x07060302u);
      pk1.x = __builtin_amdgcn_perm(__builtin_bit_cast(unsigned int, p2[1]),
                                    __builtin_bit_cast(unsigned int, p2[0]), 0x07060302u);
      pk1.y = __builtin_amdgcn_perm(__builtin_bit_cast(unsigned int, p2[3]),
                                    __builtin_bit_cast(unsigned int, p2[2]), 0x07060302u);
      pk1.z = __builtin_amdgcn_perm(__builtin_bit_cast(unsigned int, p3[1]),
                                    __builtin_bit_cast(unsigned int, p3[0]), 0x07060302u);
      pk1.w = __builtin_amdgcn_perm(__builtin_bit_cast(unsigned int, p3[3]),
                                    __builtin_bit_cast(unsigned int, p3[2]), 0x07060302u);
      bf16x8 ap0 = __builtin_bit_cast(bf16x8, pk0);
      bf16x8 ap1 = __builtin_bit_cast(bf16x8, pk1);
      accO[0][0] = __builtin_amdgcn_mfma_f32_16x16x32_bf16(ap0, bv0, accO[0][0], 0, 0, 0);
      accO[0][1] = __builtin_amdgcn_mfma_f32_16x16x32_bf16(ap0, bv1, accO[0][1], 0, 0, 0);
      accO[1][0] = __builtin_amdgcn_mfma_f32_16x16x32_bf16(ap1, bv0, accO[1][0], 0, 0, 0);
      accO[1][1] = __builtin_amdgcn_mfma_f32_16x16x32_bf16(ap1, bv1, accO[1][1], 0, 0, 0);
      accR[0] = __builtin_amdgcn_mfma_f32_16x16x32_bf16(ap0, vones, accR[0], 0, 0, 0);
      accR[1] = __builtin_amdgcn_mfma_f32_16x16x32_bf16(ap1, vones, accR[1], 0, 0, 0);
    }
    __syncthreads();
  }

  // ---- post-loop LDS regions (alias stg): pbuf | skipbuf | obuf ----
  float* pbuf = (float*)&stg[0][0][0];      // 3*4*64*24 floats = 73,728 B
  float* skipbuf = pbuf + 18432;            // 4*64*16 floats   = 16,384 B
  float* obuf = pbuf + 22528;               // 4*32*33 floats   = 16,896 B  (total 107,008)

  if (kq != 0) {
    float* pb = pbuf + (((kq - 1) * 4 + qh) * 64 + lane) * 24;
#pragma unroll
    for (int qf = 0; qf < 2; ++qf) {
#pragma unroll
      for (int dt = 0; dt < 2; ++dt)
#pragma unroll
        for (int r = 0; r < 4; ++r) pb[qf * 8 + dt * 4 + r] = accO[qf][dt][r];
#pragma unroll
      for (int r = 0; r < 4; ++r) pb[16 + qf * 4 + r] = accR[qf][r];
    }
    if (kq == 1) {
      float* sb = skipbuf + (qh * 64 + lane) * 16;
#pragma unroll
      for (int qf = 0; qf < 2; ++qf)
#pragma unroll
        for (int dt = 0; dt < 2; ++dt)
#pragma unroll
          for (int r = 0; r < 4; ++r) sb[qf * 8 + dt * 4 + r] = accS[qf][dt][r];
    }
  }
  __syncthreads();
  if (kq != 0) return;

#pragma unroll
  for (int j = 0; j < 3; ++j) {
    const float* pb = pbuf + ((j * 4 + qh) * 64 + lane) * 24;
#pragma unroll
    for (int qf = 0; qf < 2; ++qf) {
#pragma unroll
      for (int dt = 0; dt < 2; ++dt)
#pragma unroll
        for (int r = 0; r < 4; ++r) accO[qf][dt][r] += pb[qf * 8 + dt * 4 + r];
#pragma unroll
      for (int r = 0; r < 4; ++r) accR[qf][r] += pb[16 + qf * 4 + r];
    }
  }

  const float* sb = skipbuf + (qh * 64 + lane) * 16;
  float* ob = obuf + qh * 32 * 33;
#pragma unroll
  for (int qf = 0; qf < 2; ++qf) {
    float rinv[4];
#pragma unroll
    for (int r = 0; r < 4; ++r) rinv[r] = 1.0f / accR[qf][r];
#pragma unroll
    for (int dt = 0; dt < 2; ++dt)
#pragma unroll
      for (int r = 0; r < 4; ++r)
        ob[(dt * 16 + lr) * 33 + qf * 16 + quad * 4 + r] =
            accO[qf][dt][r] * rinv[r] + sb[qf * 8 + dt * 4 + r];
  }

  // ---- epilogue: out[b][h*32+d][qbase + q] = ob[d][q]  (pure fp32 write) ----
  int d = lane >> 1, q16 = (lane & 1) * 16;
  float* po = outp + ((size_t)(b * 128 + h * 32 + d)) * N_ + qbase + q16;
#pragma unroll
  for (int g = 0; g < 4; ++g) {
    float4 r0;
    r0.x = ob[d * 33 + q16 + g * 4 + 0];
    r0.y = ob[d * 33 + q16 + g * 4 + 1];
    r0.z = ob[d * 33 + q16 + g * 4 + 2];
    r0.w = ob[d * 33 + q16 + g * 4 + 3];
    *(float4*)(po + g * 4) = r0;
  }
}

extern "C" void kernel_launch(void* const* d_in, const int* in_sizes, int n_in,
                              void* d_out, int out_size, void* d_ws, size_t ws_size,
                              hipStream_t stream) {
  const float* pcd_up = (const float*)d_in[0];
  const float* psel   = (const float*)d_in[1];
  const float* pdrop  = (const float*)d_in[2];
  const float* Wq  = (const float*)d_in[4];
  const float* Wk  = (const float*)d_in[5];
  const float* Wv  = (const float*)d_in[6];
  const float* Wsk = (const float*)d_in[7];
  const int* isel  = (const int*)d_in[8];
  const int* idrop = (const int*)d_in[9];
  float* out = (float*)d_out;

  ushort_t* xT = (ushort_t*)d_ws;               // [B][N][C]      1,048,576
  ushort_t* Wb = xT + 1048576;                  // 4 x 128x128       65,536
  ushort_t* Kb = Wb + 65536;                    // [B][H][N][32]  1,048,576
  ushort_t* Vt = Kb + 1048576;                  // [B][H][32][N]  1,048,576

  hipLaunchKernelGGL(k_prep, dim3(64, 2, 2), dim3(256), 0, stream,
                     psel, pdrop, isel, idrop, Wq, Wk, Wv, Wsk, xT, Wb);
  hipLaunchKernelGGL(k_proj, dim3(64, 2, 2), dim3(256), 0, stream, xT, Wb, Kb, Vt);
  hipLaunchKernelGGL(k_attn, dim3(256), dim3(1024), 0, stream,
                     xT, pcd_up, Wb, Kb, Vt, out);
}